// Round 8
// baseline (117.495 us; speedup 1.0000x reference)
//
#include <hip/hip_runtime.h>
#include <math.h>

#define MG    2001
#define KH    1001
#define BATCH 16
#define NPTS  1024
#define RW    8
#define TAPS  17

#define LEN   32           // energy chunk per conv block
#define NMC   63           // 63*32 = 2016 >= 2001
#define CT    384          // conv block threads: ds(16) x ch(2) x mo(12)

// ws float offsets
#define GOFF  4096         // G[b][2048], b=0..15 ; f: ws[0..4095] (ch0, ch1)

static constexpr double PI = 3.14159265358979323846;

static __device__ __forceinline__ int wrapM(int m) {
  if (m < 0) m += MG;
  else if (m >= MG) m -= MG;
  return m;
}

static __device__ __forceinline__ void taps_of(float xv, int& m0, float* w) {
  const double h = 2.0*PI/(double)MG;
  const float tauf = (float)(12.0/((double)MG*(double)MG));
  const float inv4tau = (float)(1.0/(4.0*(double)tauf));
  m0 = (int)floor((double)xv/h + 0.5);
  #pragma unroll
  for (int r = 0; r < TAPS; ++r) {
    double d = (double)xv - (double)(m0 + r - RW)*h;
    float df = (float)d;
    w[r] = __expf(-(df*df)*inv4tau);
  }
}

// LDS quad swizzle: XOR bits[2:0] of quad index with bits[7:5] (breaks the
// 32-quad-stride same-bank pattern of conv's f and G reads)
static __device__ __forceinline__ int sw(int q) { return q ^ ((q >> 5) & 7); }

// ---------------- Kernel A: filter (rotation recurrence) + spread ----------------
// blocks 0..63: filt (ch = blk&1, mg = blk>>1); blocks 64..79: spread batch b=blk-64
__global__ void __launch_bounds__(256) k_pre(float* __restrict__ ws,
    const float* __restrict__ x,
    const float* __restrict__ s0p, const float* __restrict__ s1p,
    const float* __restrict__ a0p, const float* __restrict__ a1p) {
  const int tid = threadIdx.x;
  const int blk = blockIdx.x;
  if (blk < 64) {
    __shared__ float dk[1004];
    const int ch = blk & 1;
    const int mg = blk >> 1;
    {
      const float s  = ch ? s1p[0] : s0p[0];
      const float a  = ch ? a1p[0] : a0p[0];
      const float mu = ch ? 0.5f : 1.0f;
      const double tau = (double)(float)(12.0/((double)MG*(double)MG));
      const double mus = (double)(mu*s);
      const double C = 1.0/(2.0*PI*(double)MG*(double)MG);
      for (int k = tid; k < 1004; k += 256) {
        float v = 0.f;
        if (k < KH) {
          double kk = (double)k*(double)k;
          v = (float)(C*(PI/tau)*exp(2.0*kk*tau)
                      *((double)a*4.0*PI/(kk + mus*mus))*((k == 0) ? 1.0 : 2.0));
        }
        dk[k] = v;
      }
    }
    __syncthreads();
    const int ml = tid >> 2, kq = tid & 3;
    const int m = mg*64 + ml;                 // 0..2047
    float acc = 0.f;
    if (m < MG) {
      const int k0 = kq*251;
      const float ang = (float)(2.0*PI/(double)MG);
      const int j0 = (k0 * m) % MG;
      float sA, cA, sf, cf;
      __sincosf(ang * (float)j0, &sA, &cA);   // state: cos/sin(2*pi*k0*m/M)
      __sincosf(ang * (float)m,  &sf, &cf);   // step rotation by 2*pi*m/M
      #pragma unroll 4
      for (int t = 0; t < 251; ++t) {
        acc = fmaf(dk[k0 + t], cA, acc);
        const float cn = fmaf(cA, cf, -(sA*sf));
        const float sn = fmaf(sA, cf,  (cA*sf));
        cA = cn; sA = sn;
      }
    }
    acc += __shfl_xor(acc, 1);
    acc += __shfl_xor(acc, 2);
    if (kq == 0) ws[ch*2048 + m] = acc;       // m>=MG writes 0 (f zero-pad)
  } else {
    __shared__ float Gs[2004];
    const int b = blk - 64;
    for (int j = tid; j < 2004; j += 256) Gs[j] = 0.f;
    __syncthreads();
    #pragma unroll
    for (int p = 0; p < 4; ++p) {
      const float xv = x[b*NPTS + p*256 + tid];
      int m0; float w[TAPS];
      taps_of(xv, m0, w);
      #pragma unroll
      for (int r = 0; r < TAPS; ++r)
        atomicAdd(&Gs[wrapM(m0 + r - RW)], w[r]);
    }
    __syncthreads();
    for (int j = tid; j < MG; j += 256) ws[GOFF + b*2048 + j] = Gs[j];
  }
}

// ---------------- Kernel B: conv (d full range) + energy per 32-m chunk ----------------
// grid (NMC, BATCH) x 384 thr. Computes S[m] for m in [lo-8, lo+40) (48 values),
// then energies for points with m0 in [lo, lo+32).
__global__ void __launch_bounds__(CT) k_conv(const float* __restrict__ ws,
    const float* __restrict__ x, float* __restrict__ out) {
  __shared__ __align__(16) float FS[2][2048];  // swizzled f (zero-padded to 2048)
  __shared__ __align__(16) float GX[2112];     // swizzled G window [j=0..2095]
  __shared__ float Ss[128];                    // S[2][64] (48 used per ch)
  __shared__ int lst[1024];
  __shared__ int cnt;
  const int tid = threadIdx.x;
  const int mc = blockIdx.x, b = blockIdx.y;
  const int lo = mc * LEN;

  // ---- stage ----
  for (int j = tid; j < 2048; j += CT) {
    const int pos = (sw(j >> 2) << 2) | (j & 3);
    FS[0][pos] = ws[j];
    FS[1][pos] = ws[2048 + j];
  }
  const float* G = &ws[GOFF + b*2048];
  for (int j = tid; j < 2096; j += CT) {
    const int idx = (lo + j + 1946) % 2001;    // = (lo - 2056 + j) mod 2001
    GX[(sw(j >> 2) << 2) | (j & 3)] = G[idx];
  }
  if (tid < 128) Ss[tid] = 0.f;
  if (tid == 0) cnt = 0;
  __syncthreads();

  // ---- build point list (points whose m0 falls in this chunk) ----
  {
    const double inv_h = (double)MG/(2.0*PI);
    #pragma unroll
    for (int p = 0; p < 3; ++p) {
      const int n = p*CT + tid;
      if (n < NPTS) {
        const float xv = x[b*NPTS + n];
        int m0 = (int)floor((double)xv*inv_h + 0.5);
        if (m0 >= MG) m0 -= MG;
        if (m0 - lo >= 0 && m0 - lo < LEN) {
          const int i = atomicAdd(&cnt, 1);
          lst[i] = n;
        }
      }
    }
  }

  // ---- conv: S[lo-8 + mo*4 + s] += sum_d f[d]*G[m-d], d = ds*128 + 4t + u ----
  {
    const int ds = tid & 15, ch = (tid >> 4) & 1, mo = tid >> 5;   // mo 0..11
    const float* fch = FS[ch];
    float acc0 = 0.f, acc1 = 0.f, acc2 = 0.f, acc3 = 0.f;
    const int q0 = 512 + mo - 32*ds;
    float wf[8];
    *(float4*)&wf[4] = *(const float4*)&GX[sw(q0) << 2];
    #pragma unroll 4
    for (int t = 0; t < 32; ++t) {
      *(float4*)&wf[0] = *(const float4*)&GX[sw(q0 - 1 - t) << 2];
      const float4 fq = *(const float4*)&fch[sw(32*ds + t) << 2];
      // u=0
      acc0 = fmaf(fq.x, wf[4], acc0); acc1 = fmaf(fq.x, wf[5], acc1);
      acc2 = fmaf(fq.x, wf[6], acc2); acc3 = fmaf(fq.x, wf[7], acc3);
      // u=1
      acc0 = fmaf(fq.y, wf[3], acc0); acc1 = fmaf(fq.y, wf[4], acc1);
      acc2 = fmaf(fq.y, wf[5], acc2); acc3 = fmaf(fq.y, wf[6], acc3);
      // u=2
      acc0 = fmaf(fq.z, wf[2], acc0); acc1 = fmaf(fq.z, wf[3], acc1);
      acc2 = fmaf(fq.z, wf[4], acc2); acc3 = fmaf(fq.z, wf[5], acc3);
      // u=3
      acc0 = fmaf(fq.w, wf[1], acc0); acc1 = fmaf(fq.w, wf[2], acc1);
      acc2 = fmaf(fq.w, wf[3], acc2); acc3 = fmaf(fq.w, wf[4], acc3);
      wf[4] = wf[0]; wf[5] = wf[1]; wf[6] = wf[2]; wf[7] = wf[3];
    }
    float* Sp = &Ss[ch*64 + mo*4];
    atomicAdd(&Sp[0], acc0);
    atomicAdd(&Sp[1], acc1);
    atomicAdd(&Sp[2], acc2);
    atomicAdd(&Sp[3], acc3);
  }
  __syncthreads();

  // ---- energy ----
  const int ncnt = cnt;
  for (int i = tid; i < ncnt; i += CT) {
    const int n = lst[i];
    const float xv = x[b*NPTS + n];
    int m0; float w[TAPS];
    taps_of(xv, m0, w);
    int m0w = m0; if (m0w >= MG) m0w -= MG;
    const int off = m0w - lo;                  // 0..31
    float c1 = 0.f, c2 = 0.f;
    #pragma unroll
    for (int r = 0; r < TAPS; ++r) {
      c1 = fmaf(w[r], Ss[off + r], c1);
      c2 = fmaf(w[r], Ss[64 + off + r], c2);
    }
    float s1 = 0.f, s2 = 0.f;
    #pragma unroll
    for (int dl = 0; dl < TAPS; ++dl) {
      float c = 0.f;
      #pragma unroll
      for (int r = 0; r + dl < TAPS; ++r) c = fmaf(w[r], w[r + dl], c);
      const float fac = (dl == 0) ? 1.f : 2.f;
      s1 = fmaf(fac*c, FS[0][dl], s1);         // sw(q)=q for q<32: head unswizzled
      s2 = fmaf(fac*c, FS[1][dl], s2);
    }
    const int gid = b*NPTS + n;
    out[gid*2 + 0] = c1 - s1;
    out[gid*2 + 1] = c2 - s2;
  }
}

extern "C" void kernel_launch(void* const* d_in, const int* in_sizes, int n_in,
                              void* d_out, int out_size, void* d_ws, size_t ws_size,
                              hipStream_t stream) {
  const float* x  = (const float*)d_in[0];
  const float* s0 = (const float*)d_in[1];
  const float* s1 = (const float*)d_in[2];
  const float* a0 = (const float*)d_in[3];
  const float* a1 = (const float*)d_in[4];
  float* ws  = (float*)d_ws;
  float* out = (float*)d_out;

  hipLaunchKernelGGL(k_pre,  dim3(80), dim3(256), 0, stream, ws, x, s0, s1, a0, a1);
  hipLaunchKernelGGL(k_conv, dim3(NMC, BATCH), dim3(CT), 0, stream, ws, x, out);
}